// Round 5
// baseline (285.163 us; speedup 1.0000x reference)
//
#include <hip/hip_runtime.h>
#include <hip/hip_bf16.h>

#define NSEQ 2048
#define HID 128
#define HEADS 8
#define HD 16
#define SCALE 0.25f
#define TQ 16
#define TK 64
#define SPLIT 8
#define KT_PER (NSEQ / TK / SPLIT)   // 4 tiles per block
#define QROW_H 68           // q row stride in 32-bit words (64 data words + 4 pad), f16 storage
#define PM_W 36             // P row stride in 32-bit words (64 keys = 32 words + pad)
#define PH_W (16 * PM_W + 4)  // 580: P head stride in words

typedef unsigned short ushort_t;
typedef __attribute__((ext_vector_type(8))) short short8;
typedef __attribute__((ext_vector_type(4))) float floatx4;
typedef _Float16 half2_t __attribute__((ext_vector_type(2)));

#if __has_builtin(__builtin_amdgcn_fdot2)
#define FDOT2(a, b, c) __builtin_amdgcn_fdot2((a), (b), (c), false)
#else
__device__ __forceinline__ float FDOT2(half2_t a, half2_t b, float c) {
    return fmaf((float)a[0], (float)b[0], fmaf((float)a[1], (float)b[1], c));
}
#endif

__device__ __forceinline__ unsigned pack_bf16x2(float a, float b) {
    __hip_bfloat16 ba = __float2bfloat16(a);
    __hip_bfloat16 bb = __float2bfloat16(b);
    return (unsigned)*(ushort_t*)&ba | ((unsigned)*(ushort_t*)&bb << 16);
}
__device__ __forceinline__ unsigned pack_f16x2(float a, float b) {
    _Float16 ha = (_Float16)a, hb = (_Float16)b;
    return (unsigned)*(ushort_t*)&ha | ((unsigned)*(ushort_t*)&hb << 16);
}
// load 8 f16 (16B) from 16B-aligned ptr into 4 half2 regs
__device__ __forceinline__ void ld_h8(const void* p, half2_t* d) {
    uint4 v = *(const uint4*)p;
    union { unsigned u; half2_t h; } c;
    c.u = v.x; d[0] = c.h; c.u = v.y; d[1] = c.h;
    c.u = v.z; d[2] = c.h; c.u = v.w; d[3] = c.h;
}

// ---------------- kernel A: coalesced LDS-tile transpose of 4 weight matrices ----------------
__global__ __launch_bounds__(256) void transpose_kernel(
    const float* __restrict__ Wq, const float* __restrict__ Wk,
    const float* __restrict__ Wv, const float* __restrict__ Wo,
    float* __restrict__ wt)
{
    __shared__ float ts[32][33];
    const int mat = blockIdx.x >> 4, tile = blockIdx.x & 15;
    const int r0 = (tile >> 2) * 32, c0 = (tile & 3) * 32;
    const float* W = (mat == 0) ? Wq : (mat == 1) ? Wk : (mat == 2) ? Wv : Wo;
    const int lr = threadIdx.x >> 5;
    const int lc = threadIdx.x & 31;
#pragma unroll
    for (int i = 0; i < 4; ++i)
        ts[lr + i * 8][lc] = W[(r0 + lr + i * 8) * HID + c0 + lc];
    __syncthreads();
    float* dst = wt + mat * 16384;
#pragma unroll
    for (int i = 0; i < 4; ++i)
        dst[(c0 + lr + i * 8) * HID + r0 + lc] = ts[lc][lr + i * 8];
}

// ---------------- kernel B: QKV projection ----------------
// grid 1536 x 128; mat = blk>>9: 0->Q f16 rows, 1->K f16 rows, 2->V bf16 transposed Vt[j][n]
__global__ __launch_bounds__(128) void qkv_kernel(
    const float* __restrict__ x, const float* __restrict__ WqT,
    const float* __restrict__ WkT, const float* __restrict__ WvT,
    const float* __restrict__ bq, const float* __restrict__ bk,
    const float* __restrict__ bv, ushort_t* __restrict__ Qh,
    ushort_t* __restrict__ Kh, __hip_bfloat16* __restrict__ Vt)
{
    __shared__ float xs[4 * HID];
    const int j = threadIdx.x;
    const int mat = blockIdx.x >> 9;
    const int rb = blockIdx.x & 511;
    const int r0 = rb * 4;
    const float* WT = (mat == 0) ? WqT : (mat == 1) ? WkT : WvT;
    const float* bb = (mat == 0) ? bq : (mat == 1) ? bk : bv;
    ((float4*)xs)[j] = ((const float4*)(x + (size_t)r0 * HID))[j];
    __syncthreads();
    float acc[4];
#pragma unroll
    for (int r = 0; r < 4; ++r) acc[r] = 0.f;
#pragma unroll 8
    for (int i = 0; i < HID; ++i) {
        float w = WT[i * HID + j];
#pragma unroll
        for (int r = 0; r < 4; ++r) acc[r] = fmaf(xs[r * HID + i], w, acc[r]);
    }
    float bv_ = bb[j];
#pragma unroll
    for (int r = 0; r < 4; ++r) acc[r] += bv_;
    if (mat == 0) {
        ushort_t* dst = Qh;
#pragma unroll
        for (int r = 0; r < 4; ++r) {
            _Float16 h = (_Float16)acc[r];
            dst[(size_t)(r0 + r) * HID + j] = *(ushort_t*)&h;
        }
    } else if (mat == 1) {
#pragma unroll
        for (int r = 0; r < 4; ++r) {
            _Float16 h = (_Float16)acc[r];
            Kh[(size_t)(r0 + r) * HID + j] = *(ushort_t*)&h;
        }
    } else {
        unsigned u0 = pack_bf16x2(acc[0], acc[1]);
        unsigned u1 = pack_bf16x2(acc[2], acc[3]);
        *(uint2*)((ushort_t*)Vt + (size_t)j * NSEQ + r0) = make_uint2(u0, u1);
    }
}

// ---------------- kernel C: fused attention, split-K, fdot2 scores + MFMA PV ----------------
// grid 128*SPLIT x 256; block = TQ=16 query rows, 256 keys
__global__ __launch_bounds__(256, 4) void attn_kernel(
    const ushort_t* __restrict__ Qh, const ushort_t* __restrict__ Kh,
    const __hip_bfloat16* __restrict__ Vt, const float* __restrict__ bias,
    const unsigned char* __restrict__ mask, float* __restrict__ Op,
    float* __restrict__ Lp)
{
    __shared__ unsigned qs[TQ * QROW_H];   // 4.35 KB f16 q, padded
    __shared__ float Pbuf[8 * PH_W];       // 18.6 KB: P bf16 tile; reused as obuf in epilogue
    __shared__ float wl[4 * TQ * HEADS];   // 2 KB per-wave l partials

    const int t = threadIdx.x;
    const int lane = t & 63;
    const int wid = t >> 6;
    const int qb = blockIdx.x & 127;
    const int sp = blockIdx.x >> 7;
    const int n0 = qb * TQ;

    // score roles
    const int sc_mp = t >> 3;          // 0..31 -> key pair
    const int sc_h  = t & 7;
    // PV roles
    const int kk = wid & 1;
    const int hbase = (wid >> 1) * 4;
    const int frag_m = lane & 15;
    const int frag_q = lane >> 4;

    const float* bp_base = bias + ((size_t)n0 * NSEQ + sc_mp * 2) * HEADS + sc_h;
    const size_t m_base = (size_t)(sp * KT_PER) * TK;

    // ---- prologue: issue tile-0 bias loads first (longest latency) ----
    float cb0[TQ], cb1[TQ];
    {
        const float* bp = bp_base + m_base * HEADS;
#pragma unroll
        for (int r = 0; r < TQ; ++r) {
            cb0[r] = bp[(size_t)r * (NSEQ * HEADS)];
            cb1[r] = bp[(size_t)r * (NSEQ * HEADS) + HEADS];
        }
    }
    // masks for all 4 tiles (8 byte loads)
    bool mk0[KT_PER], mk1[KT_PER];
#pragma unroll
    for (int kt = 0; kt < KT_PER; ++kt) {
        const size_t m1 = m_base + kt * TK + sc_mp * 2;
        mk0[kt] = mask[m1] != 0;
        mk1[kt] = mask[m1 + 1] != 0;
    }
    // stage q tile to LDS (f16): 1 uint4 (8 f16) per thread
    {
        const int qr = t >> 4, qc = t & 15;
        uint4 v = *(const uint4*)(Qh + (size_t)(n0 + qr) * HID + qc * 8);
        *(uint4*)&qs[qr * QROW_H + qc * 4] = v;
    }
    floatx4 acc[4];
#pragma unroll
    for (int hh = 0; hh < 4; ++hh) acc[hh] = (floatx4){0.f, 0.f, 0.f, 0.f};
    float lsum[TQ];
#pragma unroll
    for (int r = 0; r < TQ; ++r) lsum[r] = 0.0f;
    __syncthreads();

#pragma unroll
    for (int kt = 0; kt < KT_PER; ++kt) {
        const size_t m0 = m_base + kt * TK;
        // K loads FIRST (compute's waitcnt drains only these)
        half2_t k0[8], k1[8];
        {
            const ushort_t* kp = Kh + (m0 + sc_mp * 2) * HID + sc_h * HD;
            ld_h8(kp, k0); ld_h8(kp + 8, k0 + 4);
            ld_h8(kp + HID, k1); ld_h8(kp + HID + 8, k1 + 4);
        }
        // then issue NEXT tile's bias loads (stay outstanding through compute)
        float nb0[TQ], nb1[TQ];
        if (kt + 1 < KT_PER) {
            const float* bp = bp_base + (m_base + (kt + 1) * TK) * HEADS;
#pragma unroll
            for (int r = 0; r < TQ; ++r) {
                nb0[r] = bp[(size_t)r * (NSEQ * HEADS)];
                nb1[r] = bp[(size_t)r * (NSEQ * HEADS) + HEADS];
            }
        }
        // ---- phase 1: f16 dot2 scores + exp -> P (bf16) ----
        {
            const bool msk0 = mk0[kt], msk1 = mk1[kt];
            unsigned* Pw = (unsigned*)Pbuf;
#pragma unroll
            for (int r = 0; r < TQ; ++r) {
                half2_t qf[8];
                const unsigned* qw = &qs[r * QROW_H + sc_h * 8];
                ld_h8(qw, qf); ld_h8(qw + 4, qf + 4);
                float d0 = 0.f, d1 = 0.f;
#pragma unroll
                for (int i = 0; i < 8; ++i) {
                    d0 = FDOT2(qf[i], k0[i], d0);
                    d1 = FDOT2(qf[i], k1[i], d1);
                }
                float s0 = fmaf(d0, SCALE, cb0[r]);
                float s1 = fmaf(d1, SCALE, cb1[r]);
                if (msk0) s0 = -INFINITY;
                if (msk1) s1 = -INFINITY;
                float e0 = __expf(s0);
                float e1 = __expf(s1);
                lsum[r] += e0 + e1;
                Pw[sc_h * PH_W + r * PM_W + sc_mp] = pack_bf16x2(e0, e1);
            }
        }
        __syncthreads();
        // ---- phase 2: PV via MFMA ----
        {
            const unsigned* Pw = (const unsigned*)Pbuf;
#pragma unroll
            for (int hh = 0; hh < 4; ++hh) {
                const int h = hbase + hh;
                const ushort_t* vrow = (const ushort_t*)Vt +
                    ((size_t)(h * HD + frag_m)) * NSEQ + m0 + kk * 32 + frag_q * 8;
                short8 bfrag = *(const short8*)vrow;
                short8 afrag = *(const short8*)&Pw[h * PH_W + frag_m * PM_W + kk * 16 + frag_q * 4];
                acc[hh] = __builtin_amdgcn_mfma_f32_16x16x32_bf16(afrag, bfrag, acc[hh], 0, 0, 0);
            }
        }
        __syncthreads();
        // rotate prefetched bias into current (SSA-renamed under full unroll)
        if (kt + 1 < KT_PER) {
#pragma unroll
            for (int r = 0; r < TQ; ++r) { cb0[r] = nb0[r]; cb1[r] = nb1[r]; }
        }
    }

    // ---- epilogue ----
#pragma unroll
    for (int r = 0; r < TQ; ++r) {
        lsum[r] += __shfl_xor(lsum[r], 8);
        lsum[r] += __shfl_xor(lsum[r], 16);
        lsum[r] += __shfl_xor(lsum[r], 32);
    }
    if (lane < 8) {
#pragma unroll
        for (int r = 0; r < TQ; ++r)
            wl[wid * (TQ * HEADS) + r * 8 + lane] = lsum[r];
    }
    {
        float* obuf = Pbuf;
#pragma unroll
        for (int hh = 0; hh < 4; ++hh) {
#pragma unroll
            for (int reg = 0; reg < 4; ++reg) {
                int m = frag_q * 4 + reg;
                obuf[kk * 2048 + (hbase + hh) * 256 + m * 16 + frag_m] = acc[hh][reg];
            }
        }
    }
    __syncthreads();
    if (t < 128) {
        const float* obuf = Pbuf;
#pragma unroll
        for (int r = 0; r < TQ; ++r) {
            int h = t >> 4, d = t & 15;
            float v = obuf[h * 256 + r * 16 + d] + obuf[2048 + h * 256 + r * 16 + d];
            Op[((size_t)sp * NSEQ + n0 + r) * HID + t] = v;
        }
        const int r2 = t >> 3, h2 = t & 7;
        float l = wl[r2 * 8 + h2] + wl[128 + r2 * 8 + h2] +
                  wl[256 + r2 * 8 + h2] + wl[384 + r2 * 8 + h2];
        Lp[((size_t)sp * NSEQ + n0 + r2) * HEADS + h2] = l;
    }
}

// ---------------- kernel D: combine splits + output projection ----------------
__global__ __launch_bounds__(128) void proj_kernel(
    const float* __restrict__ Op, const float* __restrict__ Lp,
    const float* __restrict__ WoT, const float* __restrict__ bo,
    float* __restrict__ out)
{
    __shared__ float xs[2 * HID];
    const int j = threadIdx.x;
    const int r0 = blockIdx.x * 2;
    const int hh = j >> 4;
#pragma unroll
    for (int r = 0; r < 2; ++r) {
        const size_t n = r0 + r;
        float s = 0.f, l = 0.f;
#pragma unroll
        for (int sp = 0; sp < SPLIT; ++sp) {
            s += Op[((size_t)sp * NSEQ + n) * HID + j];
            l += Lp[((size_t)sp * NSEQ + n) * HEADS + hh];
        }
        xs[r * HID + j] = s / l;
    }
    __syncthreads();
    float acc[2];
    acc[0] = 0.f; acc[1] = 0.f;
#pragma unroll 8
    for (int i = 0; i < HID; ++i) {
        float w = WoT[i * HID + j];
        acc[0] = fmaf(xs[i], w, acc[0]);
        acc[1] = fmaf(xs[HID + i], w, acc[1]);
    }
    float b = bo[j];
    out[(size_t)r0 * HID + j] = acc[0] + b;
    out[(size_t)(r0 + 1) * HID + j] = acc[1] + b;
}

extern "C" void kernel_launch(void* const* d_in, const int* in_sizes, int n_in,
                              void* d_out, int out_size, void* d_ws, size_t ws_size,
                              hipStream_t stream) {
    const float* x    = (const float*)d_in[0];
    const float* bias = (const float*)d_in[1];
    const unsigned char* mask = (const unsigned char*)d_in[2];
    const float* Wq = (const float*)d_in[3];
    const float* bq = (const float*)d_in[4];
    const float* Wk = (const float*)d_in[5];
    const float* bk = (const float*)d_in[6];
    const float* Wv = (const float*)d_in[7];
    const float* bv = (const float*)d_in[8];
    const float* Wo = (const float*)d_in[9];
    const float* bo = (const float*)d_in[10];
    float* out = (float*)d_out;

    float* w = (float*)d_ws;
    // ws layout (float offsets):
    float* WqT = w;                                     // 16384
    float* WkT = w + 16384;
    float* WvT = w + 32768;
    float* WoT = w + 49152;
    ushort_t* Qh = (ushort_t*)(w + 65536);              // 262144 f16
    ushort_t* Kh = (ushort_t*)(w + 196608);             // 262144 f16
    __hip_bfloat16* Vt = (__hip_bfloat16*)(w + 327680); // 262144 bf16 transposed [j][n]
    float* Op  = w + 458752;                            // SPLIT*262144 fp32 (8 MB)
    float* Lp  = w + 458752 + (size_t)SPLIT * NSEQ * HID;
    // total ~10.5 MB

    transpose_kernel<<<64, 256, 0, stream>>>(Wq, Wk, Wv, Wo, w);
    qkv_kernel<<<1536, 128, 0, stream>>>(x, WqT, WkT, WvT, bq, bk, bv, Qh, Kh, Vt);
    attn_kernel<<<128 * SPLIT, 256, 0, stream>>>(Qh, Kh, Vt, bias, mask, Op, Lp);
    proj_kernel<<<1024, 128, 0, stream>>>(Op, Lp, WoT, bo, out);
}